// Round 3
// baseline (495.185 us; speedup 1.0000x reference)
//
#include <hip/hip_runtime.h>
#include <hip/hip_bf16.h>
#include <cstdint>
#include <cstddef>

typedef __attribute__((ext_vector_type(8))) short bf16x8;   // 8 bf16 in 4 VGPRs
typedef __attribute__((ext_vector_type(4))) float f32x4;    // 4 fp32 acc

static __device__ __forceinline__ unsigned short f2bf(float f) {
    union { float f; unsigned u; } v; v.f = f;
    return (unsigned short)((v.u + 0x7fffu + ((v.u >> 16) & 1u)) >> 16);
}
static __device__ __forceinline__ float bf2f(unsigned short h) {
    union { unsigned u; float f; } v; v.u = ((unsigned)h) << 16;
    return v.f;
}

// 16B direct global->LDS (wave-uniform LDS base + lane*16; per-lane global src)
static __device__ __forceinline__ void gld_lds16(const unsigned short* g, unsigned short* l) {
    __builtin_amdgcn_global_load_lds(
        (const __attribute__((address_space(1))) void*)g,
        (__attribute__((address_space(3))) void*)l, 16, 0, 0);
}

#define NC 2097152      // 8192*256
#define SC 1048576      // 4096*256
#define NS 33554432     // 8192*4096
#define SPLITS 4

// ---------------------------------------------------------------------------
// K1: per-row L2 norm for all 4 inputs + zero-init of recall outputs+sumexp.
// grid (2048, 5), 256 thr = 4 waves, one row per wave.
// which: 0=speech(copy out) 1=face(copy out) 2=svm(also transpose) 3=fkm
//        4=zero out_srecall/out_frecall rows + sumexp (atomic accumulators).
// ---------------------------------------------------------------------------
__global__ __launch_bounds__(256) void rownorm_kernel(
    const float* __restrict__ face, const float* __restrict__ speech,
    const float* __restrict__ svm, const float* __restrict__ fkm,
    unsigned short* __restrict__ face_n, unsigned short* __restrict__ speech_n,
    unsigned short* __restrict__ svm_n, unsigned short* __restrict__ fkm_n,
    float* __restrict__ out_face, float* __restrict__ out_speech,
    unsigned short* __restrict__ svmT,
    float* __restrict__ out_srecall, float* __restrict__ out_frecall,
    float* __restrict__ sumexp)
{
    const int which = blockIdx.y;
    const int sub   = threadIdx.x >> 6;           // wave index = row within block
    const int lane  = threadIdx.x & 63;
    const int row   = blockIdx.x * 4 + sub;

    if (which == 4) {   // zero accumulators (K2/K4 atomically accumulate)
        const float4 z = make_float4(0.f, 0.f, 0.f, 0.f);
        *(float4*)(out_srecall + (size_t)row * 256 + lane * 4) = z;
        *(float4*)(out_frecall + (size_t)row * 256 + lane * 4) = z;
        if (lane < 2) sumexp[(size_t)lane * 8192 + row] = 0.f;
        return;
    }
    if (which >= 2 && row >= 4096) return;

    const float* in; unsigned short* nrm; float* cpy = nullptr; bool tr = false;
    if (which == 0)      { in = speech; nrm = speech_n; cpy = out_speech; }
    else if (which == 1) { in = face;   nrm = face_n;   cpy = out_face; }
    else if (which == 2) { in = svm;    nrm = svm_n;    tr = true; }
    else                 { in = fkm;    nrm = fkm_n; }

    const float4 v = *(const float4*)(in + (size_t)row * 256 + lane * 4);
    float ss = v.x * v.x + v.y * v.y + v.z * v.z + v.w * v.w;
    #pragma unroll
    for (int off = 32; off > 0; off >>= 1) ss += __shfl_xor(ss, off);
    const float rn = rsqrtf(ss);   // norms ~8-16, far above EPS=1e-8

    ushort4 o;
    o.x = f2bf(v.x * rn); o.y = f2bf(v.y * rn);
    o.z = f2bf(v.z * rn); o.w = f2bf(v.w * rn);
    *(ushort4*)(nrm + (size_t)row * 256 + lane * 4) = o;

    if (cpy) *(float4*)(cpy + (size_t)row * 256 + lane * 4) = v;

    if (tr) {   // svmT[c][s] = svm[s][c], bf16, unnormalized, stride 4096
        const int c = lane * 4;
        svmT[(size_t)(c + 0) * 4096 + row] = f2bf(v.x);
        svmT[(size_t)(c + 1) * 4096 + row] = f2bf(v.y);
        svmT[(size_t)(c + 2) * 4096 + row] = f2bf(v.z);
        svmT[(size_t)(c + 3) * 4096 + row] = f2bf(v.w);
    }
}

// ---------------------------------------------------------------------------
// K2: logits GEMM, batched over sides (z). L[m][s] = sum_c A[m][c]*B[s][c].
// 128x128 tile, 256 thr = 4 waves (2x2 of 64x64), BK=64 (8 barriers/block).
// LDS tiles [128][64] bf16, XOR-swizzled 16B slots (slot ^= row&7):
//   gld_lds writes linearly, so the SOURCE column-slot is pre-swizzled and
//   the read applies the same XOR (involution; rule both-sides-or-neither).
// Epilogue 1: per-row sum of exp(logit) -> atomicAdd sumexp (no K3 pass).
// Epilogue 2: wave-PRIVATE LDS transpose (no barriers) -> dwordx4 stores.
// ---------------------------------------------------------------------------
__global__ __launch_bounds__(256) void gemm_logits_kernel(
    const unsigned short* __restrict__ speech_n,
    const unsigned short* __restrict__ face_n,
    const unsigned short* __restrict__ svm_n,
    const unsigned short* __restrict__ fkm_n,
    unsigned short* __restrict__ logits,   // [2][8192][4096]
    float* __restrict__ sumexp)            // [2][8192]
{
    __shared__ unsigned short smem[2 * 128 * 64];   // 32 KB
    unsigned short* As = smem;              // [128][64] swizzled
    unsigned short* Bs = smem + 128 * 64;   // [128][64] swizzled
    const int side = blockIdx.z;
    const unsigned short* A = side ? face_n : speech_n;
    const unsigned short* B = side ? fkm_n  : svm_n;
    unsigned short* Lg = logits + ((size_t)side * NS);

    const int row0 = blockIdx.y * 128;
    const int col0 = blockIdx.x * 128;
    const int tid  = threadIdx.x;
    const int wave = tid >> 6, lane = tid & 63;
    const int wm = (wave >> 1) * 64, wn = (wave & 1) * 64;
    const int quad = lane >> 4, r16 = lane & 15;

    f32x4 acc[4][4];
    #pragma unroll
    for (int i = 0; i < 4; i++)
        #pragma unroll
        for (int j = 0; j < 4; j++) acc[i][j] = 0.f;

    for (int k0 = 0; k0 < 256; k0 += 64) {
        // 1024 chunks of 16B each for As/Bs; chunk c=(r,cj): r=c>>3, cj=c&7.
        // LDS dest linear (chunk*16B); global src slot = cj ^ (r&7).
        #pragma unroll
        for (int it = 0; it < 4; ++it) {
            const int c = tid + it * 256;
            const int r = c >> 3, cj = c & 7;
            const int sj = cj ^ (r & 7);
            gld_lds16(A + (size_t)(row0 + r) * 256 + k0 + sj * 8,
                      As + (size_t)(it * 256 + wave * 64) * 8);
            gld_lds16(B + (size_t)(col0 + r) * 256 + k0 + sj * 8,
                      Bs + (size_t)(it * 256 + wave * 64) * 8);
        }
        __syncthreads();   // compiler drains vmcnt before barrier

        #pragma unroll
        for (int kk = 0; kk < 2; ++kk) {       // two K=32 MFMA steps per tile
            bf16x8 af[4], bfr[4];
            #pragma unroll
            for (int i = 0; i < 4; i++) {
                const int ra = wm + i * 16 + r16;
                af[i]  = *(const bf16x8*)(&As[ra * 64 + ((kk * 4 + quad) ^ (ra & 7)) * 8]);
                const int rb = wn + i * 16 + r16;
                bfr[i] = *(const bf16x8*)(&Bs[rb * 64 + ((kk * 4 + quad) ^ (rb & 7)) * 8]);
            }
            #pragma unroll
            for (int i = 0; i < 4; i++)
                #pragma unroll
                for (int j = 0; j < 4; j++)
                    acc[i][j] = __builtin_amdgcn_mfma_f32_16x16x32_bf16(
                        af[i], bfr[j], acc[i][j], 0, 0, 0);
        }
        __syncthreads();
    }

    // ---- Epilogue 1: softmax denominator partial sums (registers only) ----
    #pragma unroll
    for (int i = 0; i < 4; i++) {
        #pragma unroll
        for (int rr = 0; rr < 4; rr++) {
            float s = 0.f;
            #pragma unroll
            for (int j = 0; j < 4; j++) s += __expf(acc[i][j][rr]);
            #pragma unroll
            for (int o = 8; o > 0; o >>= 1) s += __shfl_xor(s, o);  // sum over r16
            if (r16 == 0)
                unsafeAtomicAdd(&sumexp[(size_t)side * 8192 + row0 + wm + i * 16 + quad * 4 + rr], s);
        }
    }

    // ---- Epilogue 2: wave-PRIVATE LDS transpose (no block barriers) -------
    // Loop trailing __syncthreads guarantees all waves are done reading
    // As/Bs; each wave then uses only its own 4KB region. Intra-wave
    // ds_write->ds_read ordering is handled by compiler lgkmcnt waits.
    unsigned short* tb = smem + wave * 2048;   // [32][64] bf16 per wave
    #pragma unroll
    for (int h = 0; h < 2; ++h) {
        #pragma unroll
        for (int i2 = 0; i2 < 2; ++i2)
            #pragma unroll
            for (int j = 0; j < 4; ++j)
                #pragma unroll
                for (int rr = 0; rr < 4; ++rr)
                    tb[(i2 * 16 + quad * 4 + rr) * 64 + j * 16 + r16] =
                        f2bf(acc[2 * h + i2][j][rr]);
        #pragma unroll
        for (int p = 0; p < 4; ++p) {
            const int lrow = p * 8 + (lane >> 3);
            const int lcol = (lane & 7) * 8;
            const uint4 v = *(const uint4*)(tb + lrow * 64 + lcol);
            *(uint4*)(Lg + (size_t)(row0 + wm + h * 32 + lrow) * 4096 + col0 + wn + lcol) = v;
        }
    }
}

// ---------------------------------------------------------------------------
// K4: recall GEMM + fused log_softmax output, split-K.
// out[m][c] = sum_s exp(L[m][s]-lse[m])*svm[s][c];  slog[m][s] = L[m][s]-lse[m].
// grid (128 mtiles, SPLITS, 2 sides), 256 thr. Tile 64x256, BK=64
// (32 barriers/block, was 64). A: reg-staged with exp(x-lse) applied,
// ds_write to swizzled slots. B: gld_lds direct with pre-swizzled source.
// slog NT-stores issued AFTER the barrier so they overlap ds_read+MFMA.
// Recall accumulated into fp32 outputs with native f32 atomics (zeroed K1).
// ---------------------------------------------------------------------------
__global__ __launch_bounds__(256) void gemm_recall_kernel(
    const unsigned short* __restrict__ logits,  // [2][8192][4096]
    const float* __restrict__ sumexp,           // [2][8192]
    const unsigned short* __restrict__ BT,      // [256][4096] = svm^T bf16
    float* __restrict__ out_srecall, float* __restrict__ out_frecall,
    float* __restrict__ out_slog, float* __restrict__ out_flog)
{
    __shared__ unsigned short As[64 * 64];      // 8 KB, swizzled
    __shared__ unsigned short Bs[256 * 64];     // 32 KB, swizzled
    const int row0  = blockIdx.x * 64;
    const int split = blockIdx.y;
    const int side  = blockIdx.z;
    const unsigned short* A = logits + (size_t)side * NS;
    float* outp = side ? out_frecall : out_srecall;
    float* slog = side ? out_flog    : out_slog;
    const int kbase = split * (4096 / SPLITS);

    const int tid  = threadIdx.x;
    const int wave = tid >> 6, lane = tid & 63;
    const int wn = wave * 64;
    const int quad = lane >> 4, r16 = lane & 15;
    const int ar  = tid >> 3, acj = tid & 7;    // A chunk: rows ar / ar+32, slot acj
    const float myl0 = __logf(sumexp[(size_t)side * 8192 + row0 + ar]);
    const float myl1 = __logf(sumexp[(size_t)side * 8192 + row0 + ar + 32]);
    float* slogp0 = slog + (size_t)(row0 + ar)      * 4096 + acj * 8;
    float* slogp1 = slog + (size_t)(row0 + ar + 32) * 4096 + acj * 8;
    const int asw = (acj ^ (ar & 7)) * 8;       // (ar+32)&7 == ar&7

    f32x4 acc[4][4];
    #pragma unroll
    for (int i = 0; i < 4; i++)
        #pragma unroll
        for (int j = 0; j < 4; j++) acc[i][j] = 0.f;

    for (int k0 = kbase; k0 < kbase + 4096 / SPLITS; k0 += 64) {
        // A: two 16B loads (rows ar, ar+32), logical (unswizzled) source cols.
        uint4 a0 = *(const uint4*)(A + (size_t)(row0 + ar)      * 4096 + k0 + acj * 8);
        uint4 a1 = *(const uint4*)(A + (size_t)(row0 + ar + 32) * 4096 + k0 + acj * 8);
        // B: 2048 chunks, 8 per thread; linear LDS dest + pre-swizzled source.
        #pragma unroll
        for (int it = 0; it < 8; ++it) {
            const int c = tid + it * 256, r = c >> 3, cj = c & 7;
            gld_lds16(BT + (size_t)r * 4096 + k0 + (cj ^ (r & 7)) * 8,
                      Bs + (size_t)(it * 256 + wave * 64) * 8);
        }
        // exp(x - lse) while B loads fly; ds_write swizzled A slots.
        float xs0[8], xs1[8];
        {
            const unsigned short* v0 = (const unsigned short*)&a0;
            const unsigned short* v1 = (const unsigned short*)&a1;
            unsigned short p0[8], p1[8];
            #pragma unroll
            for (int k = 0; k < 8; k++) {
                xs0[k] = bf2f(v0[k]) - myl0;
                xs1[k] = bf2f(v1[k]) - myl1;
                p0[k] = f2bf(__expf(xs0[k]));
                p1[k] = f2bf(__expf(xs1[k]));
            }
            *(uint4*)(&As[ar * 64 + asw])        = *(uint4*)p0;
            *(uint4*)(&As[(ar + 32) * 64 + asw]) = *(uint4*)p1;
        }
        __syncthreads();

        // slog NT stores AFTER the barrier: overlap with ds_read + MFMA.
        {
            f32x4 s0, s1, s2, s3;
            #pragma unroll
            for (int k = 0; k < 4; k++) { s0[k] = xs0[k]; s1[k] = xs0[k + 4];
                                          s2[k] = xs1[k]; s3[k] = xs1[k + 4]; }
            __builtin_nontemporal_store(s0, (f32x4*)(slogp0 + k0));
            __builtin_nontemporal_store(s1, (f32x4*)(slogp0 + k0 + 4));
            __builtin_nontemporal_store(s2, (f32x4*)(slogp1 + k0));
            __builtin_nontemporal_store(s3, (f32x4*)(slogp1 + k0 + 4));
        }

        #pragma unroll
        for (int kk = 0; kk < 2; ++kk) {
            bf16x8 af[4], bfr[4];
            #pragma unroll
            for (int i = 0; i < 4; i++) {
                const int ra = i * 16 + r16;
                af[i]  = *(const bf16x8*)(&As[ra * 64 + ((kk * 4 + quad) ^ (ra & 7)) * 8]);
                const int rb = wn + i * 16 + r16;
                bfr[i] = *(const bf16x8*)(&Bs[rb * 64 + ((kk * 4 + quad) ^ (rb & 7)) * 8]);
            }
            #pragma unroll
            for (int i = 0; i < 4; i++)
                #pragma unroll
                for (int j = 0; j < 4; j++)
                    acc[i][j] = __builtin_amdgcn_mfma_f32_16x16x32_bf16(
                        af[i], bfr[j], acc[i][j], 0, 0, 0);
        }
        __syncthreads();
    }

    #pragma unroll
    for (int i = 0; i < 4; i++) {
        #pragma unroll
        for (int j = 0; j < 4; j++) {
            const int r  = row0 + i * 16 + quad * 4;
            const int cc = wn + j * 16 + r16;
            #pragma unroll
            for (int rr = 0; rr < 4; rr++)
                unsafeAtomicAdd(&outp[(size_t)(r + rr) * 256 + cc], acc[i][j][rr]);
        }
    }
}

// ---------------------------------------------------------------------------
extern "C" void kernel_launch(void* const* d_in, const int* in_sizes, int n_in,
                              void* d_out, int out_size, void* d_ws, size_t ws_size,
                              hipStream_t stream) {
    const float* face   = (const float*)d_in[0];   // [8192,256]
    const float* speech = (const float*)d_in[1];   // [8192,256]
    const float* svm    = (const float*)d_in[2];   // [4096,256]
    const float* fkm    = (const float*)d_in[3];   // [4096,256]

    const int N = 8192, S = 4096, C = 256;
    float* out = (float*)d_out;
    float* out_speech  = out;                          // [N,C]
    float* out_srecall = out + (size_t)N * C;          // [N,C]
    float* out_face    = out + 2 * (size_t)N * C;      // [N,C]
    float* out_frecall = out + 3 * (size_t)N * C;      // [N,C]
    float* out_slog    = out + 4 * (size_t)N * C;      // [N,S]
    float* out_flog    = out_slog + (size_t)N * S;     // [N,S]

    // ws layout (~140 MB of the plentiful ws)
    unsigned short* wsu = (unsigned short*)d_ws;
    unsigned short* speech_n = wsu;                      // NC
    unsigned short* face_n   = speech_n + NC;            // NC
    unsigned short* svm_n    = face_n + NC;              // SC
    unsigned short* fkm_n    = svm_n + SC;               // SC
    unsigned short* svmT     = fkm_n + SC;               // SC ([256][4096])
    unsigned short* logits   = svmT + SC;                // 2*NS bf16
    float* sumexp = (float*)(logits + 2 * (size_t)NS);   // [2][8192] fp32

    dim3 g1(N / 4, 5);
    rownorm_kernel<<<g1, 256, 0, stream>>>(face, speech, svm, fkm,
                                           face_n, speech_n, svm_n, fkm_n,
                                           out_face, out_speech, svmT,
                                           out_srecall, out_frecall, sumexp);

    dim3 g2(S / 128, N / 128, 2);
    gemm_logits_kernel<<<g2, 256, 0, stream>>>(speech_n, face_n, svm_n, fkm_n,
                                               logits, sumexp);

    dim3 g4(N / 64, SPLITS, 2);
    gemm_recall_kernel<<<g4, 256, 0, stream>>>(logits, sumexp, svmT,
                                               out_srecall, out_frecall,
                                               out_slog, out_flog);
}

// Round 4
// 467.876 us; speedup vs baseline: 1.0584x; 1.0584x over previous
//
#include <hip/hip_runtime.h>
#include <hip/hip_bf16.h>
#include <cstdint>
#include <cstddef>

typedef __attribute__((ext_vector_type(8))) short bf16x8;   // 8 bf16 in 4 VGPRs
typedef __attribute__((ext_vector_type(4))) float f32x4;    // 4 fp32 acc

static __device__ __forceinline__ unsigned short f2bf(float f) {
    union { float f; unsigned u; } v; v.f = f;
    return (unsigned short)((v.u + 0x7fffu + ((v.u >> 16) & 1u)) >> 16);
}
static __device__ __forceinline__ float bf2f(unsigned short h) {
    union { unsigned u; float f; } v; v.u = ((unsigned)h) << 16;
    return v.f;
}

// 16B direct global->LDS (wave-uniform LDS base + lane*16; per-lane global src)
static __device__ __forceinline__ void gld_lds16(const unsigned short* g, unsigned short* l) {
    __builtin_amdgcn_global_load_lds(
        (const __attribute__((address_space(1))) void*)g,
        (__attribute__((address_space(3))) void*)l, 16, 0, 0);
}

#define NC 2097152      // 8192*256
#define SC 1048576      // 4096*256
#define NS 33554432     // 8192*4096
#define SPLITS 4

// ---------------------------------------------------------------------------
// K1: per-row L2 norm for all 4 inputs + zero-init of recall outputs+sumexp.
// grid (2048, 5), 256 thr = 4 waves, one row per wave.
// which: 0=speech(copy out) 1=face(copy out) 2=svm(also transpose) 3=fkm
//        4=zero out_srecall/out_frecall rows + sumexp (atomic accumulators).
// ---------------------------------------------------------------------------
__global__ __launch_bounds__(256) void rownorm_kernel(
    const float* __restrict__ face, const float* __restrict__ speech,
    const float* __restrict__ svm, const float* __restrict__ fkm,
    unsigned short* __restrict__ face_n, unsigned short* __restrict__ speech_n,
    unsigned short* __restrict__ svm_n, unsigned short* __restrict__ fkm_n,
    float* __restrict__ out_face, float* __restrict__ out_speech,
    unsigned short* __restrict__ svmT,
    float* __restrict__ out_srecall, float* __restrict__ out_frecall,
    float* __restrict__ sumexp)
{
    const int which = blockIdx.y;
    const int sub   = threadIdx.x >> 6;           // wave index = row within block
    const int lane  = threadIdx.x & 63;
    const int row   = blockIdx.x * 4 + sub;

    if (which == 4) {   // zero accumulators (K2/K4 atomically accumulate)
        const float4 z = make_float4(0.f, 0.f, 0.f, 0.f);
        *(float4*)(out_srecall + (size_t)row * 256 + lane * 4) = z;
        *(float4*)(out_frecall + (size_t)row * 256 + lane * 4) = z;
        if (lane < 2) sumexp[(size_t)lane * 8192 + row] = 0.f;
        return;
    }
    if (which >= 2 && row >= 4096) return;

    const float* in; unsigned short* nrm; float* cpy = nullptr; bool tr = false;
    if (which == 0)      { in = speech; nrm = speech_n; cpy = out_speech; }
    else if (which == 1) { in = face;   nrm = face_n;   cpy = out_face; }
    else if (which == 2) { in = svm;    nrm = svm_n;    tr = true; }
    else                 { in = fkm;    nrm = fkm_n; }

    const float4 v = *(const float4*)(in + (size_t)row * 256 + lane * 4);
    float ss = v.x * v.x + v.y * v.y + v.z * v.z + v.w * v.w;
    #pragma unroll
    for (int off = 32; off > 0; off >>= 1) ss += __shfl_xor(ss, off);
    const float rn = rsqrtf(ss);   // norms ~8-16, far above EPS=1e-8

    ushort4 o;
    o.x = f2bf(v.x * rn); o.y = f2bf(v.y * rn);
    o.z = f2bf(v.z * rn); o.w = f2bf(v.w * rn);
    *(ushort4*)(nrm + (size_t)row * 256 + lane * 4) = o;

    if (cpy) *(float4*)(cpy + (size_t)row * 256 + lane * 4) = v;

    if (tr) {   // svmT[c][s] = svm[s][c], bf16, unnormalized, stride 4096
        const int c = lane * 4;
        svmT[(size_t)(c + 0) * 4096 + row] = f2bf(v.x);
        svmT[(size_t)(c + 1) * 4096 + row] = f2bf(v.y);
        svmT[(size_t)(c + 2) * 4096 + row] = f2bf(v.z);
        svmT[(size_t)(c + 3) * 4096 + row] = f2bf(v.w);
    }
}

// ---------------------------------------------------------------------------
// K2: logits GEMM, batched over sides (z). L[m][s] = sum_c A[m][c]*B[s][c].
// 128x128 tile, 256 thr = 4 waves (2x2 of 64x64), BK=32, K=256.
// Staging via global_load_lds (16B, linear LDS layout, linear source).
// Epilogue 1: per-row sum of exp(logit) from the fp32 accumulators,
//             shuffle-reduced over the 16-lane row group, atomicAdd into
//             sumexp[side][row]  (softmax denominator -> no softmax pass).
// Epilogue 2: wave-PRIVATE LDS transpose (no block barriers; the k-loop's
//             trailing __syncthreads guarantees all waves are done with
//             As/Bs) -> dwordx4 bf16 logits stores.
// ---------------------------------------------------------------------------
__global__ __launch_bounds__(256) void gemm_logits_kernel(
    const unsigned short* __restrict__ speech_n,
    const unsigned short* __restrict__ face_n,
    const unsigned short* __restrict__ svm_n,
    const unsigned short* __restrict__ fkm_n,
    unsigned short* __restrict__ logits,   // [2][8192][4096]
    float* __restrict__ sumexp)            // [2][8192]
{
    __shared__ unsigned short smem[128 * 32 * 2];   // 16 KB
    unsigned short* As = smem;             // [128][32]
    unsigned short* Bs = smem + 128 * 32;  // [128][32]
    const int side = blockIdx.z;
    const unsigned short* A = side ? face_n : speech_n;
    const unsigned short* B = side ? fkm_n  : svm_n;
    unsigned short* Lg = logits + ((size_t)side * NS);

    const int row0 = blockIdx.y * 128;
    const int col0 = blockIdx.x * 128;
    const int tid  = threadIdx.x;
    const int wave = tid >> 6, lane = tid & 63;
    const int wm = (wave >> 1) * 64, wn = (wave & 1) * 64;
    const int quad = lane >> 4, r16 = lane & 15;

    // chunk -> (row, 8-col group) for the two 256-chunk halves of each tile
    const int r0 = tid >> 2,          cj0 = tid & 3;
    const int r1 = (tid + 256) >> 2,  cj1 = (tid + 256) & 3;

    f32x4 acc[4][4];
    #pragma unroll
    for (int i = 0; i < 4; i++)
        #pragma unroll
        for (int j = 0; j < 4; j++) acc[i][j] = 0.f;

    for (int k0 = 0; k0 < 256; k0 += 32) {
        // 512 chunks each for As/Bs; dest is linear (chunk c -> byte c*16),
        // so LDS ptr is wave-uniform base; HW adds lane*16.
        gld_lds16(A + (size_t)(row0 + r0) * 256 + k0 + cj0 * 8, As + (size_t)(wave * 64) * 8);
        gld_lds16(B + (size_t)(col0 + r0) * 256 + k0 + cj0 * 8, Bs + (size_t)(wave * 64) * 8);
        gld_lds16(A + (size_t)(row0 + r1) * 256 + k0 + cj1 * 8, As + (size_t)(256 + wave * 64) * 8);
        gld_lds16(B + (size_t)(col0 + r1) * 256 + k0 + cj1 * 8, Bs + (size_t)(256 + wave * 64) * 8);
        __syncthreads();   // compiler drains vmcnt before barrier

        bf16x8 af[4], bfr[4];
        #pragma unroll
        for (int i = 0; i < 4; i++) {
            af[i]  = *(const bf16x8*)(&As[(wm + i * 16 + r16) * 32 + quad * 8]);
            bfr[i] = *(const bf16x8*)(&Bs[(wn + i * 16 + r16) * 32 + quad * 8]);
        }
        #pragma unroll
        for (int i = 0; i < 4; i++)
            #pragma unroll
            for (int j = 0; j < 4; j++)
                acc[i][j] = __builtin_amdgcn_mfma_f32_16x16x32_bf16(
                    af[i], bfr[j], acc[i][j], 0, 0, 0);
        __syncthreads();
    }

    // ---- Epilogue 1: softmax denominator partial sums (registers only) ----
    #pragma unroll
    for (int i = 0; i < 4; i++) {
        #pragma unroll
        for (int rr = 0; rr < 4; rr++) {
            float s = 0.f;
            #pragma unroll
            for (int j = 0; j < 4; j++) s += __expf(acc[i][j][rr]);
            #pragma unroll
            for (int o = 8; o > 0; o >>= 1) s += __shfl_xor(s, o);  // sum over r16
            if (r16 == 0)
                unsafeAtomicAdd(&sumexp[(size_t)side * 8192 + row0 + wm + i * 16 + quad * 4 + rr], s);
        }
    }

    // ---- Epilogue 2: wave-PRIVATE LDS transpose (no block barriers) -------
    // Each wave owns a disjoint 4KB region ([32][64] bf16); intra-wave
    // ds_write->ds_read ordering is handled by compiler lgkmcnt waits, and
    // same-wave DS ops execute in order, so no __syncthreads is needed.
    unsigned short* tb = smem + wave * 2048;   // [32][64] bf16 per wave
    #pragma unroll
    for (int h = 0; h < 2; ++h) {
        #pragma unroll
        for (int i2 = 0; i2 < 2; ++i2)
            #pragma unroll
            for (int j = 0; j < 4; ++j)
                #pragma unroll
                for (int rr = 0; rr < 4; ++rr)
                    tb[(i2 * 16 + quad * 4 + rr) * 64 + j * 16 + r16] =
                        f2bf(acc[2 * h + i2][j][rr]);
        #pragma unroll
        for (int p = 0; p < 4; ++p) {
            const int lrow = p * 8 + (lane >> 3);
            const int lcol = (lane & 7) * 8;
            const uint4 v = *(const uint4*)(tb + lrow * 64 + lcol);
            *(uint4*)(Lg + (size_t)(row0 + wm + h * 32 + lrow) * 4096 + col0 + wn + lcol) = v;
        }
    }
}

// ---------------------------------------------------------------------------
// K4: recall GEMM + fused log_softmax output, split-K.
// out[m][c] = sum_s exp(L[m][s]-lse[m])*svm[s][c];  slog[m][s] = L[m][s]-lse[m].
// grid (128 mtiles, SPLITS, 2 sides), 256 thr. Tile 64x256, BK=32.
// Each logits element is read exactly once across the grid (disjoint
// row-tile x split cover), so the mandatory fp32 log_softmax output is
// written here (nontemporal) during A-staging -- no separate softmax pass.
// A-tile: exp(x - lse) during reg-staging. B-tile: global_load_lds direct.
// Recall accumulated into fp32 outputs with native f32 atomics (zeroed K1).
// ---------------------------------------------------------------------------
__global__ __launch_bounds__(256) void gemm_recall_kernel(
    const unsigned short* __restrict__ logits,  // [2][8192][4096]
    const float* __restrict__ sumexp,           // [2][8192]
    const unsigned short* __restrict__ BT,      // [256][4096] = svm^T bf16
    float* __restrict__ out_srecall, float* __restrict__ out_frecall,
    float* __restrict__ out_slog, float* __restrict__ out_flog)
{
    __shared__ unsigned short As[64 * 32];      // 4 KB
    __shared__ unsigned short Bs[256 * 32];     // 16 KB
    const int row0  = blockIdx.x * 64;
    const int split = blockIdx.y;
    const int side  = blockIdx.z;
    const unsigned short* A = logits + (size_t)side * NS;
    float* outp = side ? out_frecall : out_srecall;
    float* slog = side ? out_flog    : out_slog;
    const int kbase = split * (4096 / SPLITS);

    const int tid  = threadIdx.x;
    const int wave = tid >> 6, lane = tid & 63;
    const int wn = wave * 64;
    const int quad = lane >> 4, r16 = lane & 15;
    const int arow = tid >> 2, acj = tid & 3;
    const float myl = __logf(sumexp[(size_t)side * 8192 + row0 + arow]);
    float* slogp = slog + (size_t)(row0 + arow) * 4096 + acj * 8;

    f32x4 acc[4][4];
    #pragma unroll
    for (int i = 0; i < 4; i++)
        #pragma unroll
        for (int j = 0; j < 4; j++) acc[i][j] = 0.f;

    for (int k0 = kbase; k0 < kbase + 4096 / SPLITS; k0 += 32) {
        // A: issue the global load first, B loads fly async under the exp.
        unsigned short vv[8];
        *(uint4*)vv = *(const uint4*)(A + (size_t)(row0 + arow) * 4096 + k0 + acj * 8);
        #pragma unroll
        for (int it = 0; it < 4; ++it) {   // B: 1024 chunks, linear dest
            const int c = tid + it * 256, r = c >> 2, cj = c & 3;
            gld_lds16(BT + (size_t)r * 4096 + k0 + cj * 8,
                      Bs + (size_t)(it * 256 + wave * 64) * 8);
        }
        float xs[8];
        #pragma unroll
        for (int k = 0; k < 8; k++) xs[k] = bf2f(vv[k]) - myl;
        f32x4 s0, s1;
        s0[0] = xs[0]; s0[1] = xs[1]; s0[2] = xs[2]; s0[3] = xs[3];
        s1[0] = xs[4]; s1[1] = xs[5]; s1[2] = xs[6]; s1[3] = xs[7];
        __builtin_nontemporal_store(s0, (f32x4*)(slogp + k0));
        __builtin_nontemporal_store(s1, (f32x4*)(slogp + k0 + 4));
        unsigned short pv[8];
        #pragma unroll
        for (int k = 0; k < 8; k++) pv[k] = f2bf(__expf(xs[k]));
        *(uint4*)(&As[arow * 32 + acj * 8]) = *(uint4*)pv;
        __syncthreads();

        bf16x8 af[4], bfr[4];
        #pragma unroll
        for (int i = 0; i < 4; i++) {
            af[i]  = *(const bf16x8*)(&As[(i * 16 + r16) * 32 + quad * 8]);
            bfr[i] = *(const bf16x8*)(&Bs[(wn + i * 16 + r16) * 32 + quad * 8]);
        }
        #pragma unroll
        for (int i = 0; i < 4; i++)
            #pragma unroll
            for (int j = 0; j < 4; j++)
                acc[i][j] = __builtin_amdgcn_mfma_f32_16x16x32_bf16(
                    af[i], bfr[j], acc[i][j], 0, 0, 0);
        __syncthreads();
    }

    #pragma unroll
    for (int i = 0; i < 4; i++) {
        #pragma unroll
        for (int j = 0; j < 4; j++) {
            const int r  = row0 + i * 16 + quad * 4;
            const int cc = wn + j * 16 + r16;
            #pragma unroll
            for (int rr = 0; rr < 4; rr++)
                unsafeAtomicAdd(&outp[(size_t)(r + rr) * 256 + cc], acc[i][j][rr]);
        }
    }
}

// ---------------------------------------------------------------------------
extern "C" void kernel_launch(void* const* d_in, const int* in_sizes, int n_in,
                              void* d_out, int out_size, void* d_ws, size_t ws_size,
                              hipStream_t stream) {
    const float* face   = (const float*)d_in[0];   // [8192,256]
    const float* speech = (const float*)d_in[1];   // [8192,256]
    const float* svm    = (const float*)d_in[2];   // [4096,256]
    const float* fkm    = (const float*)d_in[3];   // [4096,256]

    const int N = 8192, S = 4096, C = 256;
    float* out = (float*)d_out;
    float* out_speech  = out;                          // [N,C]
    float* out_srecall = out + (size_t)N * C;          // [N,C]
    float* out_face    = out + 2 * (size_t)N * C;      // [N,C]
    float* out_frecall = out + 3 * (size_t)N * C;      // [N,C]
    float* out_slog    = out + 4 * (size_t)N * C;      // [N,S]
    float* out_flog    = out_slog + (size_t)N * S;     // [N,S]

    // ws layout (~140 MB of the plentiful ws)
    unsigned short* wsu = (unsigned short*)d_ws;
    unsigned short* speech_n = wsu;                      // NC
    unsigned short* face_n   = speech_n + NC;            // NC
    unsigned short* svm_n    = face_n + NC;              // SC
    unsigned short* fkm_n    = svm_n + SC;               // SC
    unsigned short* svmT     = fkm_n + SC;               // SC ([256][4096])
    unsigned short* logits   = svmT + SC;                // 2*NS bf16
    float* sumexp = (float*)(logits + 2 * (size_t)NS);   // [2][8192] fp32

    dim3 g1(N / 4, 5);
    rownorm_kernel<<<g1, 256, 0, stream>>>(face, speech, svm, fkm,
                                           face_n, speech_n, svm_n, fkm_n,
                                           out_face, out_speech, svmT,
                                           out_srecall, out_frecall, sumexp);

    dim3 g2(S / 128, N / 128, 2);
    gemm_logits_kernel<<<g2, 256, 0, stream>>>(speech_n, face_n, svm_n, fkm_n,
                                               logits, sumexp);

    dim3 g4(N / 64, SPLITS, 2);
    gemm_recall_kernel<<<g4, 256, 0, stream>>>(logits, sumexp, svmT,
                                               out_srecall, out_frecall,
                                               out_slog, out_flog);
}